// Round 6
// baseline (11465.646 us; speedup 1.0000x reference)
//
#include <hip/hip_runtime.h>
#include <math.h>

// VanillaRNN, bit-exact (R4/R5 PASS) + perf restructure R6.
//
// Numerics (FROZEN — chaotic recurrence, bitwise match):
//   * z[i] = ascending-k single FMA chain k=0..255, init 0 (storage split
//     regs k<192 / LDS k>=192 does not change rounding — R4 vs R5 both pass)
//   * z = ((W_hx*x_t) + chain) + bias_h, separately rounded, left-assoc
//   * tanh = Eigen/XLA fast-tanh WITH FMA (clamp 7.99881172180175781f)
//
// R6 structure — why:
//   * R5 counters: VGPR_Count=128 + FETCH 3.7GB => w[192] not arch-resident
//     (AGPR/scratch reload per step); and wls b32 streaming = 128 KB/step/CU
//     = 1024 cyc LDS data — equal to the whole FMA floor.
//   * Fix: NC=2 columns per thread (256 WGs, 1 WG/CU, 1 wave/SIMD).
//     - 2 independent FMA chains/thread = ILP-2 covers 4-cyc FMA latency at
//       1 wave/SIMD; no second wave needed.
//     - w (KREG=192 VGPR + KLDS=64 via LDS b128) amortized over 2 columns:
//       LDS w-data halves to 64 KB/step/CU (~512 cyc, hidden under 1150 cyc
//       of FMA issue).
//     - KREG=192 + ~50 working regs fits the 256 arch budget -> no scratch.

#define TT 2048
#define BB 512
#define HH 256
#define CC 10
#define KREG 192
#define KLDS (HH - KREG)   // 64
#define NC 2

__device__ __forceinline__ float ref_tanhf(float x)
{
    const float a1  = 4.89352455891786e-03f;
    const float a3  = 6.37261928875436e-04f;
    const float a5  = 1.48572235717979e-05f;
    const float a7  = 5.12229709037114e-08f;
    const float a9  = -8.60467152213735e-11f;
    const float a11 = 2.00018790482477e-13f;
    const float a13 = -2.76076847742355e-16f;
    const float b0  = 4.89352518554385e-03f;
    const float b2  = 2.26843463243900e-03f;
    const float b4  = 1.18534705686654e-04f;
    const float b6  = 1.19825839466702e-06f;

    const float kClamp = 7.99881172180175781f;
    const float xc = fmaxf(fminf(x, kClamp), -kClamp);
    const float x2 = __fmul_rn(xc, xc);
    float p = fmaf(x2, a13, a11);
    p = fmaf(x2, p, a9);
    p = fmaf(x2, p, a7);
    p = fmaf(x2, p, a5);
    p = fmaf(x2, p, a3);
    p = fmaf(x2, p, a1);
    p = __fmul_rn(xc, p);
    float q = fmaf(x2, b6, b4);
    q = fmaf(x2, q, b2);
    q = fmaf(x2, q, b0);
    const float r = __fdiv_rn(p, q);
    return (fabsf(x) < 0.0004f) ? x : r;
}

__global__ __launch_bounds__(256, 1)
void rnn_fwd(const float* __restrict__ x,
             const float* __restrict__ W_hx,
             const float* __restrict__ W_hh,
             const float* __restrict__ W_ph,
             const float* __restrict__ bias_h,
             const float* __restrict__ bias_p,
             float* __restrict__ out)
{
    const int i  = threadIdx.x;       // hidden row 0..255
    const int b0 = blockIdx.x * NC;   // two batch columns per WG

    // LDS: w tail slice [k/4][row][4] (b128, stride-16B across lanes),
    //      h double-buffer per column (broadcast b128 reads), x rows.
    __shared__ __align__(16) float wls4[KLDS / 4][HH][4];   // 64 KB
    __shared__ __align__(16) float hbuf[2][NC][HH];         //  4 KB
    __shared__ __align__(16) float xls[NC][TT];             // 16 KB

    // --- stage: w[0..191] -> VGPRs (full unroll => constant reg indices) ---
    float w[KREG];
    const float* __restrict__ wrow = W_hh + (size_t)i * HH;
#pragma unroll
    for (int k = 0; k < KREG; k += 4) {
        const float4 v = *reinterpret_cast<const float4*>(wrow + k);
        w[k] = v.x; w[k + 1] = v.y; w[k + 2] = v.z; w[k + 3] = v.w;
    }
    // --- stage: w[192..255] -> LDS [kk][row][4] ---
#pragma unroll
    for (int kk = 0; kk < KLDS / 4; ++kk) {
        const float4 v = *reinterpret_cast<const float4*>(wrow + KREG + 4 * kk);
        *reinterpret_cast<float4*>(&wls4[kk][i][0]) = v;
    }
    // --- stage: x rows b0,b0+1 (contiguous 4096 floats) -> LDS ---
    {
        const float4* __restrict__ xsrc =
            reinterpret_cast<const float4*>(x + (size_t)b0 * TT);
        float4* __restrict__ xdst = reinterpret_cast<float4*>(&xls[0][0]);
#pragma unroll
        for (int r = 0; r < (NC * TT / 4) / HH; ++r) {
            xdst[r * HH + i] = xsrc[r * HH + i];
        }
    }

    const float whx = W_hx[i];
    const float bh  = bias_h[i];

    hbuf[0][0][i] = 0.0f;
    hbuf[0][1][i] = 0.0f;
    __syncthreads();

    for (int t = 0; t < TT; ++t) {
        const int cur = t & 1;
        const int nxt = cur ^ 1;
        const float* __restrict__ h0 = hbuf[cur][0];
        const float* __restrict__ h1 = hbuf[cur][1];

        float z0 = 0.0f, z1 = 0.0f;   // two independent ascending-k chains
#pragma unroll
        for (int k = 0; k < KREG; k += 4) {
            const float4 ha = *reinterpret_cast<const float4*>(h0 + k);
            const float4 hb = *reinterpret_cast<const float4*>(h1 + k);
            z0 = fmaf(w[k],     ha.x, z0);  z1 = fmaf(w[k],     hb.x, z1);
            z0 = fmaf(w[k + 1], ha.y, z0);  z1 = fmaf(w[k + 1], hb.y, z1);
            z0 = fmaf(w[k + 2], ha.z, z0);  z1 = fmaf(w[k + 2], hb.z, z1);
            z0 = fmaf(w[k + 3], ha.w, z0);  z1 = fmaf(w[k + 3], hb.w, z1);
        }
#pragma unroll
        for (int kk = 0; kk < KLDS / 4; ++kk) {
            const float4 wv = *reinterpret_cast<const float4*>(&wls4[kk][i][0]);
            const float4 ha = *reinterpret_cast<const float4*>(h0 + KREG + 4 * kk);
            const float4 hb = *reinterpret_cast<const float4*>(h1 + KREG + 4 * kk);
            z0 = fmaf(wv.x, ha.x, z0);  z1 = fmaf(wv.x, hb.x, z1);
            z0 = fmaf(wv.y, ha.y, z0);  z1 = fmaf(wv.y, hb.y, z1);
            z0 = fmaf(wv.z, ha.z, z0);  z1 = fmaf(wv.z, hb.z, z1);
            z0 = fmaf(wv.w, ha.w, z0);  z1 = fmaf(wv.w, hb.w, z1);
        }
        // ((W_hx*x_t) + chain) + bias_h — frozen rounding order
        const float a0 = __fmul_rn(whx, xls[0][t]);
        const float a1 = __fmul_rn(whx, xls[1][t]);
        z0 = __fadd_rn(__fadd_rn(a0, z0), bh);
        z1 = __fadd_rn(__fadd_rn(a1, z1), bh);

        hbuf[nxt][0][i] = ref_tanhf(z0);
        hbuf[nxt][1][i] = ref_tanhf(z1);
        __syncthreads();
    }

    // epilogue: p[b,c] = sum_k h_T[k]*W_ph[c,k] + bias_p[c]   (TT even -> buf 0)
    if (i < NC * CC) {
        const int col = i / CC;
        const int c   = i % CC;
        const float* __restrict__ wp = W_ph + (size_t)c * HH;
        float p = 0.0f;
#pragma unroll 8
        for (int k = 0; k < HH; ++k) {
            p = fmaf(hbuf[0][col][k], wp[k], p);
        }
        out[(size_t)(b0 + col) * CC + c] = __fadd_rn(p, bias_p[c]);
    }
}

extern "C" void kernel_launch(void* const* d_in, const int* in_sizes, int n_in,
                              void* d_out, int out_size, void* d_ws, size_t ws_size,
                              hipStream_t stream) {
    const float* x      = (const float*)d_in[0];
    const float* W_hx   = (const float*)d_in[1];
    const float* W_hh   = (const float*)d_in[2];
    const float* W_ph   = (const float*)d_in[3];
    const float* bias_h = (const float*)d_in[4];
    const float* bias_p = (const float*)d_in[5];
    float* out = (float*)d_out;

    rnn_fwd<<<dim3(BB / NC), dim3(HH), 0, stream>>>(x, W_hx, W_hh, W_ph, bias_h, bias_p, out);
}

// Round 7
// 3240.341 us; speedup vs baseline: 3.5384x; 3.5384x over previous
//
#include <hip/hip_runtime.h>
#include <math.h>

// VanillaRNN, bit-exact (R4/R5/R6 PASS) + R7 perf restructure.
//
// Numerics (FROZEN — chaotic recurrence, bitwise match):
//   * z[i] = ascending-k single FMA chain k=0..255, init 0. R7 splits the
//     chain ACROSS TWO THREADS in program order (P: k=0..127 -> exact float
//     handoff via LDS -> Q: k=128..255) — identical op sequence, bit-exact.
//   * z = ((W_hx*x_t) + chain) + bias_h, separately rounded, left-assoc
//   * tanh = Eigen/XLA fast-tanh WITH FMA (clamp 7.99881172180175781f)
//
// R7 structure — why (from R6 counters: VGPR=208 + FETCH 3.2GB = AGPR/remat
// overflow; Occ 12% = serial chain at 50% VALU cap):
//   * WG = 512 threads on 1 CU: group P (waves 0-3) holds w[i][0:128],
//     group Q (waves 4-7) holds w[i][128:256]. 128 w-regs + working ~ 210
//     VGPR < 256 -> pure arch-VGPR, no remat, no scratch.
//   * 2-stage pipeline over the CU's 2 batch columns: phase p: P does
//     half1(col p&1, step p>>1), Q does half2(col (p-1)&1, step (p-1)>>1).
//     Both groups busy in all interior phases; 2T+1 phases, barrier each.
//   * 2 waves/SIMD: paired serial fmaf chains (4-cyc dep latency, 2-cyc
//     issue) interleave to ~100% VALU. Issue floor ~512 cyc/phase/SIMD.
//   * h: same-address broadcast ds_read_b128 (conflict-free). zpart/h
//     writes: stride-1 b32 (2-way aliasing = free).

#define TT 2048
#define BB 512
#define HH 256
#define CC 10
#define KH 128   // chain half-length per thread

__device__ __forceinline__ float ref_tanhf(float x)
{
    const float a1  = 4.89352455891786e-03f;
    const float a3  = 6.37261928875436e-04f;
    const float a5  = 1.48572235717979e-05f;
    const float a7  = 5.12229709037114e-08f;
    const float a9  = -8.60467152213735e-11f;
    const float a11 = 2.00018790482477e-13f;
    const float a13 = -2.76076847742355e-16f;
    const float b0  = 4.89352518554385e-03f;
    const float b2  = 2.26843463243900e-03f;
    const float b4  = 1.18534705686654e-04f;
    const float b6  = 1.19825839466702e-06f;

    const float kClamp = 7.99881172180175781f;
    const float xc = fmaxf(fminf(x, kClamp), -kClamp);
    const float x2 = __fmul_rn(xc, xc);
    float p = fmaf(x2, a13, a11);
    p = fmaf(x2, p, a9);
    p = fmaf(x2, p, a7);
    p = fmaf(x2, p, a5);
    p = fmaf(x2, p, a3);
    p = fmaf(x2, p, a1);
    p = __fmul_rn(xc, p);
    float q = fmaf(x2, b6, b4);
    q = fmaf(x2, q, b2);
    q = fmaf(x2, q, b0);
    const float r = __fdiv_rn(p, q);
    return (fabsf(x) < 0.0004f) ? x : r;
}

__global__ __launch_bounds__(512, 2)
void rnn_fwd(const float* __restrict__ x,
             const float* __restrict__ W_hx,
             const float* __restrict__ W_hh,
             const float* __restrict__ W_ph,
             const float* __restrict__ bias_h,
             const float* __restrict__ bias_p,
             float* __restrict__ out)
{
    const int tid   = threadIdx.x;
    const int group = tid >> 8;      // 0 = P (k 0..127), 1 = Q (k 128..255)
    const int i     = tid & (HH - 1);  // hidden row
    const int b0    = blockIdx.x * 2;  // two batch columns per WG

    __shared__ __align__(16) float xls[2][TT];        // 16 KB
    __shared__ __align__(16) float hbuf[2][2][HH];    // [col][parity][row] 4 KB
    __shared__ float zpart[2][HH];                    // 2 KB

    // --- stage: this thread's half-row of W_hh -> 128 VGPRs ---
    float w[KH];
    const float* __restrict__ wrow = W_hh + (size_t)i * HH + group * KH;
#pragma unroll
    for (int k = 0; k < KH; k += 4) {
        const float4 v = *reinterpret_cast<const float4*>(wrow + k);
        w[k] = v.x; w[k + 1] = v.y; w[k + 2] = v.z; w[k + 3] = v.w;
    }
    // --- stage: x rows (2*TT contiguous floats) -> LDS, 512 threads ---
    {
        const float4* __restrict__ xsrc =
            reinterpret_cast<const float4*>(x + (size_t)b0 * TT);
        float4* __restrict__ xdst = reinterpret_cast<float4*>(&xls[0][0]);
        xdst[tid]       = xsrc[tid];
        xdst[512 + tid] = xsrc[512 + tid];
    }
    const float whx = W_hx[i];     // used by Q only
    const float bh  = bias_h[i];   // used by Q only

    // h(-1) = 0 lives at parity 1 (step t writes parity t&1, reads (t&1)^1)
    hbuf[group][1][i] = 0.0f;
    __syncthreads();

    for (int p = 0; p <= 2 * TT; ++p) {
        if (group == 0) {
            if (p < 2 * TT) {
                const int t   = p >> 1;
                const int col = p & 1;
                const float* __restrict__ h = hbuf[col][(t & 1) ^ 1];
                float z = 0.0f;   // chain start, k = 0..127
#pragma unroll
                for (int k = 0; k < KH; k += 4) {
                    const float4 h4 = *reinterpret_cast<const float4*>(h + k);
                    z = fmaf(w[k],     h4.x, z);
                    z = fmaf(w[k + 1], h4.y, z);
                    z = fmaf(w[k + 2], h4.z, z);
                    z = fmaf(w[k + 3], h4.w, z);
                }
                zpart[col][i] = z;   // exact float handoff
            }
        } else {
            if (p >= 1) {
                const int t   = (p - 1) >> 1;
                const int col = (p - 1) & 1;
                const float* __restrict__ h = hbuf[col][(t & 1) ^ 1];
                float z = zpart[col][i];   // resume chain, k = 128..255
#pragma unroll
                for (int k = 0; k < KH; k += 4) {
                    const float4 h4 = *reinterpret_cast<const float4*>(h + KH + k);
                    z = fmaf(w[k],     h4.x, z);
                    z = fmaf(w[k + 1], h4.y, z);
                    z = fmaf(w[k + 2], h4.z, z);
                    z = fmaf(w[k + 3], h4.w, z);
                }
                // ((W_hx*x_t) + chain) + bias_h — frozen rounding order
                const float a0 = __fmul_rn(whx, xls[col][t]);
                z = __fadd_rn(__fadd_rn(a0, z), bh);
                hbuf[col][t & 1][i] = ref_tanhf(z);
            }
        }
        __syncthreads();
    }

    // epilogue: p[b,c] = sum_k h_T[k]*W_ph[c,k] + bias_p[c]
    // last step t = TT-1 wrote parity (TT-1)&1 = 1
    if (tid < 2 * CC) {
        const int col = tid / CC;
        const int c   = tid % CC;
        const float* __restrict__ wp = W_ph + (size_t)c * HH;
        const float* __restrict__ hf = hbuf[col][1];
        float pv = 0.0f;
#pragma unroll 8
        for (int k = 0; k < HH; ++k) {
            pv = fmaf(hf[k], wp[k], pv);
        }
        out[(size_t)(b0 + col) * CC + c] = __fadd_rn(pv, bias_p[c]);
    }
}

extern "C" void kernel_launch(void* const* d_in, const int* in_sizes, int n_in,
                              void* d_out, int out_size, void* d_ws, size_t ws_size,
                              hipStream_t stream) {
    const float* x      = (const float*)d_in[0];
    const float* W_hx   = (const float*)d_in[1];
    const float* W_hh   = (const float*)d_in[2];
    const float* W_ph   = (const float*)d_in[3];
    const float* bias_h = (const float*)d_in[4];
    const float* bias_p = (const float*)d_in[5];
    float* out = (float*)d_out;

    rnn_fwd<<<dim3(BB / 2), dim3(512), 0, stream>>>(x, W_hx, W_hh, W_ph, bias_h, bias_p, out);
}

// Round 8
// 3131.476 us; speedup vs baseline: 3.6614x; 1.0348x over previous
//
#include <hip/hip_runtime.h>
#include <math.h>

// VanillaRNN, bit-exact (R4-R7 PASS) + R8: pin w in VGPRs.
//
// Numerics (FROZEN — chaotic recurrence, bitwise match):
//   * z[i] = ascending-k single FMA chain k=0..255, init 0, split across two
//     threads in program order (P: k=0..127 -> exact float LDS handoff ->
//     Q: k=128..255) — identical op sequence, bit-exact (R7 passed).
//   * z = ((W_hx*x_t) + chain) + bias_h, separately rounded, left-assoc
//   * tanh = Eigen/XLA fast-tanh WITH FMA (clamp 7.99881172180175781f)
//
// R8 change — why: R7 counters showed VGPR_Count=80 + FETCH 3.2GB: the
// compiler REMATERIALIZED the loop-invariant w loads inside the K-loop
// (re-reading W_hh from L2/L3 every phase) instead of keeping w[128]
// resident. The asm volatile("" : "+v") identity after staging makes each
// w value an opaque asm output — remat impossible, w stays in arch VGPRs
// (128 + ~60 working < 256 cap at launch_bounds(512,2)).
//
// Structure (R7, kept): WG=512 on 1 CU; P=waves 0-3 (k 0..127), Q=waves 4-7
// (k 128..255); 2-stage pipeline over the CU's 2 batch columns, 2T+1 phases;
// 2 waves/SIMD pair P+Q chains to cover 4-cyc FMA dep latency; h reads are
// same-address broadcast ds_read_b128; zpart/h writes stride-1 (free).

#define TT 2048
#define BB 512
#define HH 256
#define CC 10
#define KH 128   // chain half-length per thread

__device__ __forceinline__ float ref_tanhf(float x)
{
    const float a1  = 4.89352455891786e-03f;
    const float a3  = 6.37261928875436e-04f;
    const float a5  = 1.48572235717979e-05f;
    const float a7  = 5.12229709037114e-08f;
    const float a9  = -8.60467152213735e-11f;
    const float a11 = 2.00018790482477e-13f;
    const float a13 = -2.76076847742355e-16f;
    const float b0  = 4.89352518554385e-03f;
    const float b2  = 2.26843463243900e-03f;
    const float b4  = 1.18534705686654e-04f;
    const float b6  = 1.19825839466702e-06f;

    const float kClamp = 7.99881172180175781f;
    const float xc = fmaxf(fminf(x, kClamp), -kClamp);
    const float x2 = __fmul_rn(xc, xc);
    float p = fmaf(x2, a13, a11);
    p = fmaf(x2, p, a9);
    p = fmaf(x2, p, a7);
    p = fmaf(x2, p, a5);
    p = fmaf(x2, p, a3);
    p = fmaf(x2, p, a1);
    p = __fmul_rn(xc, p);
    float q = fmaf(x2, b6, b4);
    q = fmaf(x2, q, b2);
    q = fmaf(x2, q, b0);
    const float r = __fdiv_rn(p, q);
    return (fabsf(x) < 0.0004f) ? x : r;
}

__global__ __launch_bounds__(512, 2)
void rnn_fwd(const float* __restrict__ x,
             const float* __restrict__ W_hx,
             const float* __restrict__ W_hh,
             const float* __restrict__ W_ph,
             const float* __restrict__ bias_h,
             const float* __restrict__ bias_p,
             float* __restrict__ out)
{
    const int tid   = threadIdx.x;
    const int group = tid >> 8;        // 0 = P (k 0..127), 1 = Q (k 128..255)
    const int i     = tid & (HH - 1);  // hidden row
    const int b0    = blockIdx.x * 2;  // two batch columns per WG

    __shared__ __align__(16) float xls[2][TT];        // 16 KB
    __shared__ __align__(16) float hbuf[2][2][HH];    // [col][parity][row] 4 KB
    __shared__ float zpart[2][HH];                    // 2 KB

    // --- stage: this thread's half-row of W_hh -> 128 VGPRs ---
    float w[KH];
    const float* __restrict__ wrow = W_hh + (size_t)i * HH + group * KH;
#pragma unroll
    for (int k = 0; k < KH; k += 4) {
        const float4 v = *reinterpret_cast<const float4*>(wrow + k);
        w[k] = v.x; w[k + 1] = v.y; w[k + 2] = v.z; w[k + 3] = v.w;
    }
    // Opaque identity: makes each w[k] an asm output -> the compiler cannot
    // rematerialize the global load inside the loop; w stays VGPR-resident.
#pragma unroll
    for (int k = 0; k < KH; ++k) {
        asm volatile("" : "+v"(w[k]));
    }

    // --- stage: x rows (2*TT contiguous floats) -> LDS, 512 threads ---
    {
        const float4* __restrict__ xsrc =
            reinterpret_cast<const float4*>(x + (size_t)b0 * TT);
        float4* __restrict__ xdst = reinterpret_cast<float4*>(&xls[0][0]);
        xdst[tid]       = xsrc[tid];
        xdst[512 + tid] = xsrc[512 + tid];
    }
    const float whx = W_hx[i];     // used by Q only
    const float bh  = bias_h[i];   // used by Q only

    // h(-1) = 0 lives at parity 1 (step t writes parity t&1, reads (t&1)^1)
    hbuf[group][1][i] = 0.0f;
    __syncthreads();

    for (int p = 0; p <= 2 * TT; ++p) {
        if (group == 0) {
            if (p < 2 * TT) {
                const int t   = p >> 1;
                const int col = p & 1;
                const float* __restrict__ h = hbuf[col][(t & 1) ^ 1];
                float z = 0.0f;   // chain start, k = 0..127
#pragma unroll
                for (int k = 0; k < KH; k += 4) {
                    const float4 h4 = *reinterpret_cast<const float4*>(h + k);
                    z = fmaf(w[k],     h4.x, z);
                    z = fmaf(w[k + 1], h4.y, z);
                    z = fmaf(w[k + 2], h4.z, z);
                    z = fmaf(w[k + 3], h4.w, z);
                }
                zpart[col][i] = z;   // exact float handoff
            }
        } else {
            if (p >= 1) {
                const int t   = (p - 1) >> 1;
                const int col = (p - 1) & 1;
                const float* __restrict__ h = hbuf[col][(t & 1) ^ 1];
                float z = zpart[col][i];   // resume chain, k = 128..255
#pragma unroll
                for (int k = 0; k < KH; k += 4) {
                    const float4 h4 = *reinterpret_cast<const float4*>(h + KH + k);
                    z = fmaf(w[k],     h4.x, z);
                    z = fmaf(w[k + 1], h4.y, z);
                    z = fmaf(w[k + 2], h4.z, z);
                    z = fmaf(w[k + 3], h4.w, z);
                }
                // ((W_hx*x_t) + chain) + bias_h — frozen rounding order
                const float a0 = __fmul_rn(whx, xls[col][t]);
                z = __fadd_rn(__fadd_rn(a0, z), bh);
                hbuf[col][t & 1][i] = ref_tanhf(z);
            }
        }
        __syncthreads();
    }

    // epilogue: p[b,c] = sum_k h_T[k]*W_ph[c,k] + bias_p[c]
    // last step t = TT-1 wrote parity (TT-1)&1 = 1
    if (tid < 2 * CC) {
        const int col = tid / CC;
        const int c   = tid % CC;
        const float* __restrict__ wp = W_ph + (size_t)c * HH;
        const float* __restrict__ hf = hbuf[col][1];
        float pv = 0.0f;
#pragma unroll 8
        for (int k = 0; k < HH; ++k) {
            pv = fmaf(hf[k], wp[k], pv);
        }
        out[(size_t)(b0 + col) * CC + c] = __fadd_rn(pv, bias_p[c]);
    }
}

extern "C" void kernel_launch(void* const* d_in, const int* in_sizes, int n_in,
                              void* d_out, int out_size, void* d_ws, size_t ws_size,
                              hipStream_t stream) {
    const float* x      = (const float*)d_in[0];
    const float* W_hx   = (const float*)d_in[1];
    const float* W_hh   = (const float*)d_in[2];
    const float* W_ph   = (const float*)d_in[3];
    const float* bias_h = (const float*)d_in[4];
    const float* bias_p = (const float*)d_in[5];
    float* out = (float*)d_out;

    rnn_fwd<<<dim3(BB / 2), dim3(512), 0, stream>>>(x, W_hx, W_hh, W_ph, bias_h, bias_p, out);
}

// Round 9
// 3049.423 us; speedup vs baseline: 3.7599x; 1.0269x over previous
//
#include <hip/hip_runtime.h>
#include <math.h>

// VanillaRNN, bit-exact (R4-R8 PASS) + R9: kill per-phase VALU inflation.
//
// Numerics (FROZEN — chaotic recurrence, bitwise match):
//   * z[i] = ascending-k single FMA chain k=0..255, init 0, split across two
//     thread groups in program order (P: k=0..127 -> exact float LDS handoff
//     -> Q: k=128..255) — identical op sequence, bit-exact (R7/R8 passed).
//   * z = ((W_hx*x_t) + chain) + bias_h, separately rounded, left-assoc
//   * tanh = Eigen/XLA fast-tanh WITH FMA (clamp 7.99881172180175781f)
//
// R9 change — why: R8 counters: VALU cyc/step = 0.63*3670 ~= 2270 vs ~1140
// in source => ~1100 cyc/step of address/guard/parity recomputation (col, t,
// (t&1)^1 pointer selects feeding 32 ds_read addresses, per-phase guards,
// 4097 iterations). Fix: t-loop unrolled x2 with COMPILE-TIME read-parity
// and col literals in every body (macro-expanded) -> all LDS accesses are
// base + immediate offset (ds_read_b128 offset:imm, zero per-read VALU).
// Schedule (audited u=0,1,2 + tail, bit-identical order):
//   phaseA(u): P(col0, t=u, rp)        | Q(col1, t=u-1, rp^1)  [u>=1]
//   phaseB(u): P(col1, t=u, rp)        | Q(col0, t=u,   rp)
//   epilogue:  Q(col1, t=T-1, rp=0)
// where rp = (u&1)^1 = read parity; Q writes parity rp^1.

#define TT 2048
#define BB 512
#define HH 256
#define CC 10
#define KH 128   // chain half-length per thread group

__device__ __forceinline__ float ref_tanhf(float x)
{
    const float a1  = 4.89352455891786e-03f;
    const float a3  = 6.37261928875436e-04f;
    const float a5  = 1.48572235717979e-05f;
    const float a7  = 5.12229709037114e-08f;
    const float a9  = -8.60467152213735e-11f;
    const float a11 = 2.00018790482477e-13f;
    const float a13 = -2.76076847742355e-16f;
    const float b0  = 4.89352518554385e-03f;
    const float b2  = 2.26843463243900e-03f;
    const float b4  = 1.18534705686654e-04f;
    const float b6  = 1.19825839466702e-06f;

    const float kClamp = 7.99881172180175781f;
    const float xc = fmaxf(fminf(x, kClamp), -kClamp);
    const float x2 = __fmul_rn(xc, xc);
    float p = fmaf(x2, a13, a11);
    p = fmaf(x2, p, a9);
    p = fmaf(x2, p, a7);
    p = fmaf(x2, p, a5);
    p = fmaf(x2, p, a3);
    p = fmaf(x2, p, a1);
    p = __fmul_rn(xc, p);
    float q = fmaf(x2, b6, b4);
    q = fmaf(x2, q, b2);
    q = fmaf(x2, q, b0);
    const float r = __fdiv_rn(p, q);
    return (fabsf(x) < 0.0004f) ? x : r;
}

__global__ __launch_bounds__(512, 2)
void rnn_fwd(const float* __restrict__ x,
             const float* __restrict__ W_hx,
             const float* __restrict__ W_hh,
             const float* __restrict__ W_ph,
             const float* __restrict__ bias_h,
             const float* __restrict__ bias_p,
             float* __restrict__ out)
{
    const int tid   = threadIdx.x;
    const int group = tid >> 8;        // 0 = P (k 0..127), 1 = Q (k 128..255)
    const int i     = tid & (HH - 1);  // hidden row
    const int b0    = blockIdx.x * 2;  // two batch columns per WG

    __shared__ __align__(16) float xls[2][TT];        // 16 KB
    __shared__ __align__(16) float hbuf[2][2][HH];    // [col][parity][row] 4 KB
    __shared__ __align__(16) float zpart[2][HH];      // 2 KB

    // --- stage: this thread's half-row of W_hh -> 128 VGPRs/AGPRs ---
    float w[KH];
    const float* __restrict__ wrow = W_hh + (size_t)i * HH + group * KH;
#pragma unroll
    for (int k = 0; k < KH; k += 4) {
        const float4 v = *reinterpret_cast<const float4*>(wrow + k);
        w[k] = v.x; w[k + 1] = v.y; w[k + 2] = v.z; w[k + 3] = v.w;
    }
#pragma unroll
    for (int k = 0; k < KH; ++k) {
        asm volatile("" : "+v"(w[k]));   // block rematerialization
    }

    // --- stage: x rows (2*TT contiguous floats) -> LDS, 512 threads ---
    {
        const float4* __restrict__ xsrc =
            reinterpret_cast<const float4*>(x + (size_t)b0 * TT);
        float4* __restrict__ xdst = reinterpret_cast<float4*>(&xls[0][0]);
        xdst[tid]       = xsrc[tid];
        xdst[512 + tid] = xsrc[512 + tid];
    }
    const float whx = W_hx[i];     // used by Q only
    const float bh  = bias_h[i];   // used by Q only

    // h(-1)=0 at parity 1 (step t reads (t&1)^1, writes t&1)
    hbuf[group][1][i] = 0.0f;
    __syncthreads();

// P half-chain: k = 0..127, init 0, store exact partial.
#define PBODY(COL, T, RP)                                                     \
    {                                                                         \
        const float* __restrict__ h = &hbuf[(COL)][(RP)][0];                  \
        float z = 0.0f;                                                       \
        _Pragma("unroll")                                                     \
        for (int k = 0; k < KH; k += 4) {                                     \
            const float4 h4 = *reinterpret_cast<const float4*>(h + k);        \
            z = fmaf(w[k],     h4.x, z);                                      \
            z = fmaf(w[k + 1], h4.y, z);                                      \
            z = fmaf(w[k + 2], h4.z, z);                                      \
            z = fmaf(w[k + 3], h4.w, z);                                      \
        }                                                                     \
        zpart[(COL)][i] = z;                                                  \
    }

// Q half-chain: resume k = 128..255, then x/bias/tanh, write parity RP^1.
#define QBODY(COL, T, RP)                                                     \
    {                                                                         \
        const float* __restrict__ h = &hbuf[(COL)][(RP)][0];                  \
        float z = zpart[(COL)][i];                                            \
        _Pragma("unroll")                                                     \
        for (int k = 0; k < KH; k += 4) {                                     \
            const float4 h4 = *reinterpret_cast<const float4*>(h + KH + k);   \
            z = fmaf(w[k],     h4.x, z);                                      \
            z = fmaf(w[k + 1], h4.y, z);                                      \
            z = fmaf(w[k + 2], h4.z, z);                                      \
            z = fmaf(w[k + 3], h4.w, z);                                      \
        }                                                                     \
        const float a0 = __fmul_rn(whx, xls[(COL)][(T)]);                     \
        z = __fadd_rn(__fadd_rn(a0, z), bh);                                  \
        hbuf[(COL)][(RP) ^ 1][i] = ref_tanhf(z);                              \
    }

// One u-iteration with compile-time read-parity RP = (u&1)^1.
#define STEP(U, RP)                                                           \
    {                                                                         \
        if (group == 0) { PBODY(0, (U), (RP)) }                               \
        else if ((U) >= 1) { QBODY(1, (U) - 1, (RP) ^ 1) }                    \
        __syncthreads();                                                      \
        if (group == 0) { PBODY(1, (U), (RP)) }                               \
        else { QBODY(0, (U), (RP)) }                                          \
        __syncthreads();                                                      \
    }

    // u=0 peeled (resolves the u>=1 guard), then pairs with constant parity.
    STEP(0, 1)
    for (int u = 1; u + 1 < TT; u += 2) {
        STEP(u, 0)
        STEP(u + 1, 1)
    }
    STEP(TT - 1, 0)                       // u = 2047 (odd -> rp = 0)
    if (group == 1) { QBODY(1, TT - 1, 0) }   // drain pipeline: col1, last step
    __syncthreads();

#undef STEP
#undef QBODY
#undef PBODY

    // epilogue: p[b,c] = sum_k h_T[k]*W_ph[c,k] + bias_p[c]
    // last step t = TT-1 wrote parity (TT-1)&1 = 1
    if (tid < 2 * CC) {
        const int col = tid / CC;
        const int c   = tid % CC;
        const float* __restrict__ wp = W_ph + (size_t)c * HH;
        const float* __restrict__ hf = hbuf[col][1];
        float pv = 0.0f;
#pragma unroll 8
        for (int k = 0; k < HH; ++k) {
            pv = fmaf(hf[k], wp[k], pv);
        }
        out[(size_t)(b0 + col) * CC + c] = __fadd_rn(pv, bias_p[c]);
    }
}

extern "C" void kernel_launch(void* const* d_in, const int* in_sizes, int n_in,
                              void* d_out, int out_size, void* d_ws, size_t ws_size,
                              hipStream_t stream) {
    const float* x      = (const float*)d_in[0];
    const float* W_hx   = (const float*)d_in[1];
    const float* W_hh   = (const float*)d_in[2];
    const float* W_ph   = (const float*)d_in[3];
    const float* bias_h = (const float*)d_in[4];
    const float* bias_p = (const float*)d_in[5];
    float* out = (float*)d_out;

    rnn_fwd<<<dim3(BB / 2), dim3(512), 0, stream>>>(x, W_hx, W_hh, W_ph, bias_h, bias_p, out);
}